// Round 11
// baseline (5341.998 us; speedup 1.0000x reference)
//
#include <hip/hip_runtime.h>
#include <hip/hip_bf16.h>
#include <stdint.h>

#define TT 1024
#define BB 32
#define DD 1024

typedef __attribute__((ext_vector_type(8))) short short8;
typedef __attribute__((ext_vector_type(4))) unsigned short ushort4v;
typedef __attribute__((ext_vector_type(4))) float floatx4;
typedef __attribute__((ext_vector_type(4))) unsigned uint4v;

static __device__ __forceinline__ unsigned short f2bf(float f){
  unsigned u = __float_as_uint(f);
  u += 0x7fffu + ((u >> 16) & 1u);   // RNE
  return (unsigned short)(u >> 16);
}
static __device__ __forceinline__ float bf2f(unsigned short s){
  return __uint_as_float(((unsigned)s) << 16);
}
static __device__ __forceinline__ float sigm(float x){
  return __fdividef(1.0f, 1.0f + __expf(-x));
}
static __device__ __forceinline__ float fast_tanh(float x){
  float e = __expf(2.0f * x);
  return 1.0f - __fdividef(2.0f, e + 1.0f);
}

// ---------------- workspace layout ----------------
// frag: [t][bh(2)][64KB block]: alpha fragments (32KB) + wx fragments (32KB).
// Dead block (t-1,bh) is reused at step t as tagged h exchange ull[16][512]:
// granule = { lo32 = packed bf16 pair, hi32 = ((t+1)<<16)|(t+1) }. Fire-and-
// forget relaxed agent atomic stores; relaxed agent atomic loads; tag match ==
// current (8B single-copy atomicity). No fences/flags/drains. Tag collisions
// impossible: bf16 fragment residue hi16s are never 0x0001..0x0401 (denormals),
// poison 0xAAAAAAAA invalid, replay residue deterministic-identical (benign).
#define WS_FRAG_BYTES (134217728ull)
#define WS_WCAT_OFF   (WS_FRAG_BYTES)
#define WS_WCAT_BYTES (4194304ull)
#define WS_H0T_OFF    (WS_WCAT_OFF + WS_WCAT_BYTES)
#define WS_H1T_OFF    (WS_H0T_OFF + 131072ull)

__global__ void init_kernel(const float* __restrict__ Wa, const float* __restrict__ Wx,
                            const float* __restrict__ h0, float* __restrict__ hout0,
                            unsigned short* __restrict__ Wcat,
                            unsigned long long* __restrict__ h0T,
                            unsigned long long* __restrict__ h1T)
{
  long i = (long)blockIdx.x * 256 + threadIdx.x;
  const long NW = 2048L * 1024L;
  for (long idx = i; idx < NW; idx += (long)gridDim.x * 256L){
    long r = idx >> 10, c = idx & 1023;
    float v = (r < 1024) ? Wa[r*1024 + c] : Wx[(r-1024)*1024 + c];
    Wcat[idx] = f2bf(v);
  }
  const long NG = 32L * 512L;
  for (long idx = i; idx < NG; idx += (long)gridDim.x * 256L){
    long row = idx >> 9, cp = idx & 511;
    float a = h0[row*1024 + 2*cp], b = h0[row*1024 + 2*cp + 1];
    unsigned hpair = ((unsigned)f2bf(b) << 16) | (unsigned)f2bf(a);
    h0T[idx] = ((unsigned long long)0x00010001u << 32) | hpair;
    h1T[idx] = 0ull;
  }
  const long NH = 32L * 1024L;
  for (long idx = i; idx < NH; idx += (long)gridDim.x * 256L)
    hout0[idx] = h0[idx];
}

__global__ __launch_bounds__(256) void pre_gemm(
    const float* __restrict__ x, const unsigned short* __restrict__ Wcat,
    const float* __restrict__ b_alpha, const float* __restrict__ b_x,
    unsigned short* __restrict__ frag)
{
  __shared__ unsigned short A_lds[128*72];
  __shared__ unsigned short B_lds[128*72];
  const int tid = threadIdx.x;
  const int lane = tid & 63;
  const int w = tid >> 6;
  const int wm = w >> 1, wn = w & 1;
  const long m0 = (long)blockIdx.y * 128;
  const int n0 = blockIdx.x * 128;

  floatx4 acc[4][4];
#pragma unroll
  for (int i=0;i<4;++i)
#pragma unroll
    for (int j=0;j<4;++j) acc[i][j] = (floatx4){0.f,0.f,0.f,0.f};

  for (int kt=0; kt<16; ++kt){
    const int k0 = kt*64;
    __syncthreads();
#pragma unroll
    for (int rep=0; rep<4; ++rep){
      int flat = rep*2048 + tid*8;
      int r = flat >> 6, c = flat & 63;
      const float* src = &x[(m0 + r)*1024 + k0 + c];
      floatx4 f0 = *(const floatx4*)src;
      floatx4 f1 = *(const floatx4*)(src + 4);
      short8 v;
      v[0]=(short)f2bf(f0[0]); v[1]=(short)f2bf(f0[1]); v[2]=(short)f2bf(f0[2]); v[3]=(short)f2bf(f0[3]);
      v[4]=(short)f2bf(f1[0]); v[5]=(short)f2bf(f1[1]); v[6]=(short)f2bf(f1[2]); v[7]=(short)f2bf(f1[3]);
      *(short8*)&A_lds[r*72 + c] = v;
      short8 bv = *(const short8*)&Wcat[(long)(n0 + r)*1024 + k0 + c];
      *(short8*)&B_lds[r*72 + c] = bv;
    }
    __syncthreads();
#pragma unroll
    for (int kb=0; kb<2; ++kb){
      short8 a[4], b[4];
#pragma unroll
      for (int f=0; f<4; ++f)
        a[f] = *(const short8*)&A_lds[(wm*64 + f*16 + (lane&15))*72 + kb*32 + (lane>>4)*8];
#pragma unroll
      for (int f=0; f<4; ++f)
        b[f] = *(const short8*)&B_lds[(wn*64 + f*16 + (lane&15))*72 + kb*32 + (lane>>4)*8];
#pragma unroll
      for (int fm=0; fm<4; ++fm)
#pragma unroll
        for (int fn=0; fn<4; ++fn)
          acc[fm][fn] = __builtin_amdgcn_mfma_f32_16x16x32_bf16(a[fm], b[fn], acc[fm][fn], 0, 0, 0);
    }
  }

#pragma unroll
  for (int fm=0; fm<4; ++fm){
    const long mrow = m0 + wm*64 + fm*16;
    const int t  = (int)(mrow >> 5);
    const int bh = (int)((mrow >> 4) & 1);
#pragma unroll
    for (int fn=0; fn<4; ++fn){
      const int nf  = n0 + wn*64 + fn*16;
      const int nt  = nf >> 4;
      const int col = nf + (lane & 15);
      floatx4 v = acc[fm][fn];
      const float bias = (col < DD) ? b_alpha[col] : b_x[col - DD];
      ushort4v o;
#pragma unroll
      for (int i=0;i<4;++i) o[i] = f2bf(v[i] + bias);
      *(ushort4v*)&frag[((((long)t*2 + bh)*128 + nt)*64 + lane)*4] = o;
    }
  }
}

// ---------------- scan: tagged exchange, pipelined poll, ping-pong LDS, W in regs
// Per step: validate preloaded tagged granules (retry on stale), stage into
// h_lds[t&1] (bank-half swizzle), ONE barrier, MFMA vs Breg, epilogue + fire-
// and-forget tagged stores, then immediately issue next step's granule loads
// (overlaps store-visibility + detection with this step's tail).
__global__ __launch_bounds__(256, 1) void scan_kernel(
    const float* __restrict__ Wh, const float* __restrict__ h0,
    unsigned short* frag,
    unsigned long long* h0T,
    unsigned long long* h1T)
{
  __shared__ unsigned h_lds[2][16*512];  // 64KB ping-pong, swizzled granules
  const int tid  = threadIdx.x;
  const int lane = tid & 63;
  const int w    = tid >> 6;
  const int bh   = blockIdx.x & 1;
  const int s    = blockIdx.x >> 1;
  const int base_r = s * 64;

  const int g8   = (lane >> 4) * 8;
  const int brow = w*16 + (lane & 15);

  // W_h slice row -> registers (fp32 load + convert, one-time)
  short8 Breg[32];
  {
    const float* Wr = &Wh[(long)(base_r + brow)*1024 + g8];
#pragma unroll
    for (int kb=0; kb<32; ++kb){
      floatx4 f0 = *(const floatx4*)&Wr[kb*32];
      floatx4 f1 = *(const floatx4*)&Wr[kb*32 + 4];
      short8 v;
      v[0]=(short)f2bf(f0[0]); v[1]=(short)f2bf(f0[1]); v[2]=(short)f2bf(f0[2]); v[3]=(short)f2bf(f0[3]);
      v[4]=(short)f2bf(f1[0]); v[5]=(short)f2bf(f1[1]); v[6]=(short)f2bf(f1[2]); v[7]=(short)f2bf(f1[3]);
      Breg[kb] = v;
    }
  }

  const int colf = base_r + w*16 + (lane & 15);
  const int nt_a = (base_r + w*16) >> 4;
  float hp[4];
#pragma unroll
  for (int i=0;i<4;++i){
    int gb = bh*16 + (lane>>4)*4 + i;
    hp[i] = h0[(long)gb*1024 + colf];
  }

  const int rowq  = w*4 + (lane>>4);     // staging: wave w owns rows w*4..w*4+3
  const int cpl   = lane & 15;
  const int row_a = lane & 15;           // MFMA A row
  // bank-half swizzle: sw(row) = ((row&7)<<2) ^ ((row&1)<<4)
  const int sww = ((rowq  & 7) << 2) ^ ((rowq  & 1) << 4);
  const int swr = ((row_a & 7) << 2) ^ ((row_a & 1) << 4);

  long fb = (((long)0*2 + bh)*128 + nt_a)*64 + lane;
  ushort4v al = *(const ushort4v*)&frag[fb*4];
  ushort4v wx = *(const ushort4v*)&frag[(fb + 64*64)*4];

  const int ceven = colf & ~1;
  const bool iseven = ((lane & 1) == 0);

  // preload tagged granules for t=0
  unsigned long long d[32];
  {
    const unsigned long long* hU = h0T + bh*8192;
#pragma unroll
    for (int j=0; j<32; ++j)
      d[j] = __hip_atomic_load(&hU[rowq*512 + cpl + 16*j],
                               __ATOMIC_RELAXED, __HIP_MEMORY_SCOPE_AGENT);
  }

  for (int t=0; t<TT; ++t){
    const unsigned long long* hU =
        (t == 0) ? (h0T + bh*8192) :
        (t == 1) ? (h1T + bh*8192) :
                   (const unsigned long long*)(frag + ((long)(t-2)*2 + bh)*32768);
    const unsigned tt = ((unsigned)(t+1) << 16) | (unsigned)(t+1);

    // validate preloaded granules; reload only on stale tags
    for (;;){
      unsigned bad = 0;
#pragma unroll
      for (int j=0; j<32; ++j)
        bad |= ((unsigned)(d[j] >> 32)) ^ tt;
      if (__all(bad == 0)) break;
#pragma unroll
      for (int j=0; j<32; ++j)
        d[j] = __hip_atomic_load(&hU[rowq*512 + cpl + 16*j],
                                 __ATOMIC_RELAXED, __HIP_MEMORY_SCOPE_AGENT);
    }

    // stage to ping-pong LDS (strip tags), bank-half swizzled
    unsigned* Hbuf = h_lds[t & 1];
#pragma unroll
    for (int j=0; j<32; ++j){
      const int cp = cpl + 16*j;
      Hbuf[rowq*512 + (((cp & ~3) ^ sww) | (cp & 3))] = (unsigned)d[j];
    }
    __syncthreads();   // the ONLY barrier per step

    floatx4 ac0 = (floatx4){0.f,0.f,0.f,0.f}, ac1 = ac0, ac2 = ac0, ac3 = ac0;
#pragma unroll
    for (int kb=0; kb<32; ++kb){
      uint4v q = *(const uint4v*)&Hbuf[row_a*512 + ((kb*16 + (g8>>1)) ^ swr)];
      short8 afr = __builtin_bit_cast(short8, q);
      if ((kb&3)==0) ac0 = __builtin_amdgcn_mfma_f32_16x16x32_bf16(afr, Breg[kb], ac0, 0, 0, 0);
      if ((kb&3)==1) ac1 = __builtin_amdgcn_mfma_f32_16x16x32_bf16(afr, Breg[kb], ac1, 0, 0, 0);
      if ((kb&3)==2) ac2 = __builtin_amdgcn_mfma_f32_16x16x32_bf16(afr, Breg[kb], ac2, 0, 0, 0);
      if ((kb&3)==3) ac3 = __builtin_amdgcn_mfma_f32_16x16x32_bf16(afr, Breg[kb], ac3, 0, 0, 0);
    }
    floatx4 acc = (ac0 + ac1) + (ac2 + ac3);

    // epilogue: h_{t+1}, pack pairs via shfl, tagged fire-and-forget stores
    unsigned long long* hD =
        (t == 0) ? (h1T + bh*8192)
                 : (unsigned long long*)(frag + ((long)(t-1)*2 + bh)*32768);
    const unsigned ttn = ((unsigned)(t+2) << 16) | (unsigned)(t+2);
#pragma unroll
    for (int i=0;i<4;++i){
      float sv = acc[i] + bf2f(wx[i]);
      float v  = fast_tanh(sv);
      float aa = sigm(bf2f(al[i]));
      float hn = aa*hp[i] + (1.0f - aa)*v;
      hp[i] = hn;
      unsigned us    = (unsigned)f2bf(hn);
      unsigned other = (unsigned)__shfl_xor((int)us, 1, 64);
      if (iseven){
        unsigned hpair = (other << 16) | us;
        unsigned long long pv = ((unsigned long long)ttn << 32) | hpair;
        const int r = (lane>>4)*4 + i;
        __hip_atomic_store(&hD[r*512 + (ceven>>1)], pv,
                           __ATOMIC_RELAXED, __HIP_MEMORY_SCOPE_AGENT);
      }
    }

    // pipelined poll: issue next step's granule loads NOW (own-store race ->
    // stale tag -> handled by retry). Overlaps store-visibility + detection.
    if (t + 1 < TT){
      const unsigned long long* hU2 =
          (t + 1 == 1) ? (h1T + bh*8192)
                       : (const unsigned long long*)(frag + ((long)(t-1)*2 + bh)*32768);
#pragma unroll
      for (int j=0; j<32; ++j)
        d[j] = __hip_atomic_load(&hU2[rowq*512 + cpl + 16*j],
                                 __ATOMIC_RELAXED, __HIP_MEMORY_SCOPE_AGENT);
      fb = (((long)(t+1)*2 + bh)*128 + nt_a)*64 + lane;
      al = *(const ushort4v*)&frag[fb*4];
      wx = *(const ushort4v*)&frag[(fb + 64*64)*4];
    }
  }
}

__global__ __launch_bounds__(256) void out_writer(
    const unsigned short* __restrict__ frag,
    const unsigned long long* __restrict__ h1T,
    float* __restrict__ out, float* __restrict__ hout)
{
  const int t1 = blockIdx.z + 1;
  const int bh = blockIdx.y;
  const int e  = (blockIdx.x*256 + threadIdx.x)*8;
  const int row = e >> 10, col = e & 1023;
  const unsigned long long* src =
      (t1 == 1) ? (h1T + bh*8192)
                : (const unsigned long long*)(frag + ((long)(t1-2)*2 + bh)*32768);
  const unsigned long long* p = &src[row*512 + (col>>1)];
  float o[8], hh[8];
#pragma unroll
  for (int g=0; g<4; ++g){
    unsigned hpair = (unsigned)p[g];
    float ha = bf2f((unsigned short)(hpair & 0xFFFFu));
    float hb = bf2f((unsigned short)(hpair >> 16));
    float sa = sigm(ha), sb = sigm(hb);
    hh[2*g] = ha;            hh[2*g+1] = hb;
    o[2*g]  = ha*ha*sa;      o[2*g+1]  = hb*hb*sb;
  }
  long ob = ((long)(t1-1)*BB + bh*16 + row)*DD + col;
  long hb = ((long)t1*BB + bh*16 + row)*DD + col;
  *(floatx4*)&out[ob]     = (floatx4){o[0],o[1],o[2],o[3]};
  *(floatx4*)&out[ob+4]   = (floatx4){o[4],o[5],o[6],o[7]};
  *(floatx4*)&hout[hb]    = (floatx4){hh[0],hh[1],hh[2],hh[3]};
  *(floatx4*)&hout[hb+4]  = (floatx4){hh[4],hh[5],hh[6],hh[7]};
}

extern "C" void kernel_launch(void* const* d_in, const int* in_sizes, int n_in,
                              void* d_out, int out_size, void* d_ws, size_t ws_size,
                              hipStream_t stream)
{
  const float* x  = (const float*)d_in[0];
  const float* h0 = (const float*)d_in[1];
  const float* Wa = (const float*)d_in[2];
  const float* ba = (const float*)d_in[3];
  const float* Wh = (const float*)d_in[4];
  const float* Wx = (const float*)d_in[5];
  const float* bx = (const float*)d_in[6];

  float* out  = (float*)d_out;
  float* hout = out + (long)TT*BB*DD;

  uint8_t* ws = (uint8_t*)d_ws;
  unsigned short*     frag = (unsigned short*)(ws);
  unsigned short*     Wcat = (unsigned short*)(ws + WS_WCAT_OFF);
  unsigned long long* h0T  = (unsigned long long*)(ws + WS_H0T_OFF);
  unsigned long long* h1T  = (unsigned long long*)(ws + WS_H1T_OFF);

  init_kernel<<<8192, 256, 0, stream>>>(Wa, Wx, h0, hout, Wcat, h0T, h1T);
  pre_gemm<<<dim3(16, 256), 256, 0, stream>>>(x, Wcat, ba, bx, frag);
  scan_kernel<<<32, 256, 0, stream>>>(Wh, h0, frag, h0T, h1T);
  out_writer<<<dim3(8, 2, 1024), 256, 0, stream>>>(frag, h1T, out, hout);
}

// Round 12
// 4014.233 us; speedup vs baseline: 1.3308x; 1.3308x over previous
//
#include <hip/hip_runtime.h>
#include <hip/hip_bf16.h>
#include <stdint.h>

#define TT 1024
#define BB 32
#define DD 1024

typedef __attribute__((ext_vector_type(8))) short short8;
typedef __attribute__((ext_vector_type(4))) unsigned short ushort4v;
typedef __attribute__((ext_vector_type(4))) float floatx4;
typedef __attribute__((ext_vector_type(4))) unsigned uint4v;

static __device__ __forceinline__ unsigned short f2bf(float f){
  unsigned u = __float_as_uint(f);
  u += 0x7fffu + ((u >> 16) & 1u);   // RNE
  return (unsigned short)(u >> 16);
}
static __device__ __forceinline__ float bf2f(unsigned short s){
  return __uint_as_float(((unsigned)s) << 16);
}
static __device__ __forceinline__ float sigm(float x){
  return __fdividef(1.0f, 1.0f + __expf(-x));
}
static __device__ __forceinline__ float fast_tanh(float x){
  float e = __expf(2.0f * x);
  return 1.0f - __fdividef(2.0f, e + 1.0f);
}

// ---------------- workspace layout ----------------
// frag: [t][bh(2)][64KB block]: alpha fragments (32KB) + wx fragments (32KB).
// Dead block (t-1,bh) is reused at step t as tagged h exchange ull[16][512]:
// granule = { lo32 = packed bf16 pair, hi32 = ((t+1)<<16)|(t+1) }. Fire-and-
// forget relaxed agent atomic stores; relaxed agent atomic loads; tag match ==
// current (8B single-copy atomicity). No fences/flags/drains. Tag collisions
// impossible: bf16 fragment residue hi16s are never 0x0001..0x0401 (denormals),
// poison 0xAAAAAAAA invalid, replay residue deterministic-identical (benign).
#define WS_FRAG_BYTES (134217728ull)
#define WS_WCAT_OFF   (WS_FRAG_BYTES)
#define WS_WCAT_BYTES (4194304ull)
#define WS_H0T_OFF    (WS_WCAT_OFF + WS_WCAT_BYTES)
#define WS_H1T_OFF    (WS_H0T_OFF + 131072ull)

__global__ void init_kernel(const float* __restrict__ Wa, const float* __restrict__ Wx,
                            const float* __restrict__ h0, float* __restrict__ hout0,
                            unsigned short* __restrict__ Wcat,
                            unsigned long long* __restrict__ h0T,
                            unsigned long long* __restrict__ h1T)
{
  long i = (long)blockIdx.x * 256 + threadIdx.x;
  const long NW = 2048L * 1024L;
  for (long idx = i; idx < NW; idx += (long)gridDim.x * 256L){
    long r = idx >> 10, c = idx & 1023;
    float v = (r < 1024) ? Wa[r*1024 + c] : Wx[(r-1024)*1024 + c];
    Wcat[idx] = f2bf(v);
  }
  const long NG = 32L * 512L;
  for (long idx = i; idx < NG; idx += (long)gridDim.x * 256L){
    long row = idx >> 9, cp = idx & 511;
    float a = h0[row*1024 + 2*cp], b = h0[row*1024 + 2*cp + 1];
    unsigned hpair = ((unsigned)f2bf(b) << 16) | (unsigned)f2bf(a);
    h0T[idx] = ((unsigned long long)0x00010001u << 32) | hpair;
    h1T[idx] = 0ull;
  }
  const long NH = 32L * 1024L;
  for (long idx = i; idx < NH; idx += (long)gridDim.x * 256L)
    hout0[idx] = h0[idx];
}

__global__ __launch_bounds__(256) void pre_gemm(
    const float* __restrict__ x, const unsigned short* __restrict__ Wcat,
    const float* __restrict__ b_alpha, const float* __restrict__ b_x,
    unsigned short* __restrict__ frag)
{
  __shared__ unsigned short A_lds[128*72];
  __shared__ unsigned short B_lds[128*72];
  const int tid = threadIdx.x;
  const int lane = tid & 63;
  const int w = tid >> 6;
  const int wm = w >> 1, wn = w & 1;
  const long m0 = (long)blockIdx.y * 128;
  const int n0 = blockIdx.x * 128;

  floatx4 acc[4][4];
#pragma unroll
  for (int i=0;i<4;++i)
#pragma unroll
    for (int j=0;j<4;++j) acc[i][j] = (floatx4){0.f,0.f,0.f,0.f};

  for (int kt=0; kt<16; ++kt){
    const int k0 = kt*64;
    __syncthreads();
#pragma unroll
    for (int rep=0; rep<4; ++rep){
      int flat = rep*2048 + tid*8;
      int r = flat >> 6, c = flat & 63;
      const float* src = &x[(m0 + r)*1024 + k0 + c];
      floatx4 f0 = *(const floatx4*)src;
      floatx4 f1 = *(const floatx4*)(src + 4);
      short8 v;
      v[0]=(short)f2bf(f0[0]); v[1]=(short)f2bf(f0[1]); v[2]=(short)f2bf(f0[2]); v[3]=(short)f2bf(f0[3]);
      v[4]=(short)f2bf(f1[0]); v[5]=(short)f2bf(f1[1]); v[6]=(short)f2bf(f1[2]); v[7]=(short)f2bf(f1[3]);
      *(short8*)&A_lds[r*72 + c] = v;
      short8 bv = *(const short8*)&Wcat[(long)(n0 + r)*1024 + k0 + c];
      *(short8*)&B_lds[r*72 + c] = bv;
    }
    __syncthreads();
#pragma unroll
    for (int kb=0; kb<2; ++kb){
      short8 a[4], b[4];
#pragma unroll
      for (int f=0; f<4; ++f)
        a[f] = *(const short8*)&A_lds[(wm*64 + f*16 + (lane&15))*72 + kb*32 + (lane>>4)*8];
#pragma unroll
      for (int f=0; f<4; ++f)
        b[f] = *(const short8*)&B_lds[(wn*64 + f*16 + (lane&15))*72 + kb*32 + (lane>>4)*8];
#pragma unroll
      for (int fm=0; fm<4; ++fm)
#pragma unroll
        for (int fn=0; fn<4; ++fn)
          acc[fm][fn] = __builtin_amdgcn_mfma_f32_16x16x32_bf16(a[fm], b[fn], acc[fm][fn], 0, 0, 0);
    }
  }

#pragma unroll
  for (int fm=0; fm<4; ++fm){
    const long mrow = m0 + wm*64 + fm*16;
    const int t  = (int)(mrow >> 5);
    const int bh = (int)((mrow >> 4) & 1);
#pragma unroll
    for (int fn=0; fn<4; ++fn){
      const int nf  = n0 + wn*64 + fn*16;
      const int nt  = nf >> 4;
      const int col = nf + (lane & 15);
      floatx4 v = acc[fm][fn];
      const float bias = (col < DD) ? b_alpha[col] : b_x[col - DD];
      ushort4v o;
#pragma unroll
      for (int i=0;i<4;++i) o[i] = f2bf(v[i] + bias);
      *(ushort4v*)&frag[((((long)t*2 + bh)*128 + nt)*64 + lane)*4] = o;
    }
  }
}

// ---------------- scan: tagged exchange, split-K two-phase overlap, W in regs
// Per step: issue ALL granule loads just-in-time at loop top; validate+stage
// half A (producers 0..7), barrier, MFMA A while half B's staleness resolves;
// validate+stage B, barrier, MFMA B; epilogue + fire-and-forget tagged stores.
// Ping-pong LDS removes the end-of-step barrier.
__global__ __launch_bounds__(256, 1) void scan_kernel(
    const float* __restrict__ Wh, const float* __restrict__ h0,
    unsigned short* frag,
    unsigned long long* h0T,
    unsigned long long* h1T)
{
  __shared__ unsigned h_lds[2][16*512];  // 64KB ping-pong, swizzled granules
  const int tid  = threadIdx.x;
  const int lane = tid & 63;
  const int w    = tid >> 6;
  const int bh   = blockIdx.x & 1;
  const int s    = blockIdx.x >> 1;
  const int base_r = s * 64;

  const int g8   = (lane >> 4) * 8;
  const int brow = w*16 + (lane & 15);

  // W_h slice row -> registers (fp32 load + convert, one-time)
  short8 Breg[32];
  {
    const float* Wr = &Wh[(long)(base_r + brow)*1024 + g8];
#pragma unroll
    for (int kb=0; kb<32; ++kb){
      floatx4 f0 = *(const floatx4*)&Wr[kb*32];
      floatx4 f1 = *(const floatx4*)&Wr[kb*32 + 4];
      short8 v;
      v[0]=(short)f2bf(f0[0]); v[1]=(short)f2bf(f0[1]); v[2]=(short)f2bf(f0[2]); v[3]=(short)f2bf(f0[3]);
      v[4]=(short)f2bf(f1[0]); v[5]=(short)f2bf(f1[1]); v[6]=(short)f2bf(f1[2]); v[7]=(short)f2bf(f1[3]);
      Breg[kb] = v;
    }
  }

  const int colf = base_r + w*16 + (lane & 15);
  const int nt_a = (base_r + w*16) >> 4;
  float hp[4];
#pragma unroll
  for (int i=0;i<4;++i){
    int gb = bh*16 + (lane>>4)*4 + i;
    hp[i] = h0[(long)gb*1024 + colf];
  }

  const int rowq  = w*4 + (lane>>4);     // staging: wave w owns rows w*4..w*4+3
  const int cpl   = lane & 15;
  const int row_a = lane & 15;           // MFMA A row
  // bank-half swizzle: sw(row) = ((row&7)<<2) ^ ((row&1)<<4)
  const int sww = ((rowq  & 7) << 2) ^ ((rowq  & 1) << 4);
  const int swr = ((row_a & 7) << 2) ^ ((row_a & 1) << 4);

  long fb = (((long)0*2 + bh)*128 + nt_a)*64 + lane;
  ushort4v al = *(const ushort4v*)&frag[fb*4];
  ushort4v wx = *(const ushort4v*)&frag[(fb + 64*64)*4];

  const int ceven = colf & ~1;
  const bool iseven = ((lane & 1) == 0);

  for (int t=0; t<TT; ++t){
    const unsigned long long* hU =
        (t == 0) ? (h0T + bh*8192) :
        (t == 1) ? (h1T + bh*8192) :
                   (const unsigned long long*)(frag + ((long)(t-2)*2 + bh)*32768);
    const unsigned tt = ((unsigned)(t+1) << 16) | (unsigned)(t+1);
    unsigned* Hbuf = h_lds[t & 1];

    // just-in-time: issue BOTH halves' loads now
    unsigned long long dA[16], dB[16];
#pragma unroll
    for (int j=0; j<16; ++j)
      dA[j] = __hip_atomic_load(&hU[rowq*512 + cpl + 16*j],
                                __ATOMIC_RELAXED, __HIP_MEMORY_SCOPE_AGENT);
#pragma unroll
    for (int j=0; j<16; ++j)
      dB[j] = __hip_atomic_load(&hU[rowq*512 + cpl + 16*(16+j)],
                                __ATOMIC_RELAXED, __HIP_MEMORY_SCOPE_AGENT);

    // ---- half A: validate (retry A only), stage, barrier, MFMA kb 0..15
    for (;;){
      unsigned bad = 0;
#pragma unroll
      for (int j=0; j<16; ++j)
        bad |= ((unsigned)(dA[j] >> 32)) ^ tt;
      if (__all(bad == 0)) break;
#pragma unroll
      for (int j=0; j<16; ++j)
        dA[j] = __hip_atomic_load(&hU[rowq*512 + cpl + 16*j],
                                  __ATOMIC_RELAXED, __HIP_MEMORY_SCOPE_AGENT);
    }
#pragma unroll
    for (int j=0; j<16; ++j){
      const int cp = cpl + 16*j;
      Hbuf[rowq*512 + (((cp & ~3) ^ sww) | (cp & 3))] = (unsigned)dA[j];
    }
    __syncthreads();   // half A staged

    floatx4 ac0 = (floatx4){0.f,0.f,0.f,0.f}, ac1 = ac0, ac2 = ac0, ac3 = ac0;
#pragma unroll
    for (int kb=0; kb<16; ++kb){
      uint4v q = *(const uint4v*)&Hbuf[row_a*512 + ((kb*16 + (g8>>1)) ^ swr)];
      short8 afr = __builtin_bit_cast(short8, q);
      if ((kb&3)==0) ac0 = __builtin_amdgcn_mfma_f32_16x16x32_bf16(afr, Breg[kb], ac0, 0, 0, 0);
      if ((kb&3)==1) ac1 = __builtin_amdgcn_mfma_f32_16x16x32_bf16(afr, Breg[kb], ac1, 0, 0, 0);
      if ((kb&3)==2) ac2 = __builtin_amdgcn_mfma_f32_16x16x32_bf16(afr, Breg[kb], ac2, 0, 0, 0);
      if ((kb&3)==3) ac3 = __builtin_amdgcn_mfma_f32_16x16x32_bf16(afr, Breg[kb], ac3, 0, 0, 0);
    }

    // ---- half B: validate (loads long in flight), stage, barrier, MFMA 16..31
    for (;;){
      unsigned bad = 0;
#pragma unroll
      for (int j=0; j<16; ++j)
        bad |= ((unsigned)(dB[j] >> 32)) ^ tt;
      if (__all(bad == 0)) break;
#pragma unroll
      for (int j=0; j<16; ++j)
        dB[j] = __hip_atomic_load(&hU[rowq*512 + cpl + 16*(16+j)],
                                  __ATOMIC_RELAXED, __HIP_MEMORY_SCOPE_AGENT);
    }
#pragma unroll
    for (int j=0; j<16; ++j){
      const int cp = cpl + 16*(16+j);
      Hbuf[rowq*512 + (((cp & ~3) ^ sww) | (cp & 3))] = (unsigned)dB[j];
    }
    __syncthreads();   // half B staged

#pragma unroll
    for (int kb=16; kb<32; ++kb){
      uint4v q = *(const uint4v*)&Hbuf[row_a*512 + ((kb*16 + (g8>>1)) ^ swr)];
      short8 afr = __builtin_bit_cast(short8, q);
      if ((kb&3)==0) ac0 = __builtin_amdgcn_mfma_f32_16x16x32_bf16(afr, Breg[kb], ac0, 0, 0, 0);
      if ((kb&3)==1) ac1 = __builtin_amdgcn_mfma_f32_16x16x32_bf16(afr, Breg[kb], ac1, 0, 0, 0);
      if ((kb&3)==2) ac2 = __builtin_amdgcn_mfma_f32_16x16x32_bf16(afr, Breg[kb], ac2, 0, 0, 0);
      if ((kb&3)==3) ac3 = __builtin_amdgcn_mfma_f32_16x16x32_bf16(afr, Breg[kb], ac3, 0, 0, 0);
    }
    floatx4 acc = (ac0 + ac1) + (ac2 + ac3);

    // epilogue: h_{t+1}, pack pairs via shfl, tagged fire-and-forget stores
    unsigned long long* hD =
        (t == 0) ? (h1T + bh*8192)
                 : (unsigned long long*)(frag + ((long)(t-1)*2 + bh)*32768);
    const unsigned ttn = ((unsigned)(t+2) << 16) | (unsigned)(t+2);
#pragma unroll
    for (int i=0;i<4;++i){
      float sv = acc[i] + bf2f(wx[i]);
      float v  = fast_tanh(sv);
      float aa = sigm(bf2f(al[i]));
      float hn = aa*hp[i] + (1.0f - aa)*v;
      hp[i] = hn;
      unsigned us    = (unsigned)f2bf(hn);
      unsigned other = (unsigned)__shfl_xor((int)us, 1, 64);
      if (iseven){
        unsigned hpair = (other << 16) | us;
        unsigned long long pv = ((unsigned long long)ttn << 32) | hpair;
        const int r = (lane>>4)*4 + i;
        __hip_atomic_store(&hD[r*512 + (ceven>>1)], pv,
                           __ATOMIC_RELAXED, __HIP_MEMORY_SCOPE_AGENT);
      }
    }

    // prefetch next alpha/wx (plain cached; frag[t+1] untouched until step t+2)
    if (t + 1 < TT){
      fb = (((long)(t+1)*2 + bh)*128 + nt_a)*64 + lane;
      al = *(const ushort4v*)&frag[fb*4];
      wx = *(const ushort4v*)&frag[(fb + 64*64)*4];
    }
  }
}

__global__ __launch_bounds__(256) void out_writer(
    const unsigned short* __restrict__ frag,
    const unsigned long long* __restrict__ h1T,
    float* __restrict__ out, float* __restrict__ hout)
{
  const int t1 = blockIdx.z + 1;
  const int bh = blockIdx.y;
  const int e  = (blockIdx.x*256 + threadIdx.x)*8;
  const int row = e >> 10, col = e & 1023;
  const unsigned long long* src =
      (t1 == 1) ? (h1T + bh*8192)
                : (const unsigned long long*)(frag + ((long)(t1-2)*2 + bh)*32768);
  const unsigned long long* p = &src[row*512 + (col>>1)];
  float o[8], hh[8];
#pragma unroll
  for (int g=0; g<4; ++g){
    unsigned hpair = (unsigned)p[g];
    float ha = bf2f((unsigned short)(hpair & 0xFFFFu));
    float hb = bf2f((unsigned short)(hpair >> 16));
    float sa = sigm(ha), sb = sigm(hb);
    hh[2*g] = ha;            hh[2*g+1] = hb;
    o[2*g]  = ha*ha*sa;      o[2*g+1]  = hb*hb*sb;
  }
  long ob = ((long)(t1-1)*BB + bh*16 + row)*DD + col;
  long hb = ((long)t1*BB + bh*16 + row)*DD + col;
  *(floatx4*)&out[ob]     = (floatx4){o[0],o[1],o[2],o[3]};
  *(floatx4*)&out[ob+4]   = (floatx4){o[4],o[5],o[6],o[7]};
  *(floatx4*)&hout[hb]    = (floatx4){hh[0],hh[1],hh[2],hh[3]};
  *(floatx4*)&hout[hb+4]  = (floatx4){hh[4],hh[5],hh[6],hh[7]};
}

extern "C" void kernel_launch(void* const* d_in, const int* in_sizes, int n_in,
                              void* d_out, int out_size, void* d_ws, size_t ws_size,
                              hipStream_t stream)
{
  const float* x  = (const float*)d_in[0];
  const float* h0 = (const float*)d_in[1];
  const float* Wa = (const float*)d_in[2];
  const float* ba = (const float*)d_in[3];
  const float* Wh = (const float*)d_in[4];
  const float* Wx = (const float*)d_in[5];
  const float* bx = (const float*)d_in[6];

  float* out  = (float*)d_out;
  float* hout = out + (long)TT*BB*DD;

  uint8_t* ws = (uint8_t*)d_ws;
  unsigned short*     frag = (unsigned short*)(ws);
  unsigned short*     Wcat = (unsigned short*)(ws + WS_WCAT_OFF);
  unsigned long long* h0T  = (unsigned long long*)(ws + WS_H0T_OFF);
  unsigned long long* h1T  = (unsigned long long*)(ws + WS_H1T_OFF);

  init_kernel<<<8192, 256, 0, stream>>>(Wa, Wx, h0, hout, Wcat, h0T, h1T);
  pre_gemm<<<dim3(16, 256), 256, 0, stream>>>(x, Wcat, ba, bx, frag);
  scan_kernel<<<32, 256, 0, stream>>>(Wh, h0, frag, h0T, h1T);
  out_writer<<<dim3(8, 2, 1024), 256, 0, stream>>>(frag, h1T, out, hout);
}

// Round 13
// 3510.069 us; speedup vs baseline: 1.5219x; 1.1436x over previous
//
#include <hip/hip_runtime.h>
#include <hip/hip_bf16.h>
#include <stdint.h>

#define TT 1024
#define BB 32
#define DD 1024

typedef __attribute__((ext_vector_type(8))) short short8;
typedef __attribute__((ext_vector_type(4))) unsigned short ushort4v;
typedef __attribute__((ext_vector_type(4))) float floatx4;
typedef __attribute__((ext_vector_type(4))) unsigned uint4v;

static __device__ __forceinline__ unsigned short f2bf(float f){
  unsigned u = __float_as_uint(f);
  u += 0x7fffu + ((u >> 16) & 1u);   // RNE
  return (unsigned short)(u >> 16);
}
static __device__ __forceinline__ float bf2f(unsigned short s){
  return __uint_as_float(((unsigned)s) << 16);
}
static __device__ __forceinline__ float sigm(float x){
  return __fdividef(1.0f, 1.0f + __expf(-x));
}
static __device__ __forceinline__ float fast_tanh(float x){
  float e = __expf(2.0f * x);
  return 1.0f - __fdividef(2.0f, e + 1.0f);
}

// ---------------- workspace layout ----------------
// frag: [t][bh(2)][64KB block] = alpha fragments (first 32KB) + wx (second 32KB).
// h EXCHANGE (sentinel-gated, UNtagged):
//   h_{t+1} = plain bf16 [16 rows][1024 cols] (32KB) written over the DEAD alpha
//   half of block (t-1,bh) with relaxed agent ATOMIC 8B stores (-> MALL).
//   Producer wave then s_waitcnt vmcnt(0) and atomically bumps its SENTINEL
//   (R8-proven: drain-then-signal makes data globally visible before signal).
//   Consumer polls 64 sentinels (1/lane), then PLAIN-loads the data:
//   guaranteed fresh because alpha halves are only ever read ATOMICALLY (no
//   L1/L2 copy exists before the h store), wx half is in different cache lines,
//   and no block is ever reused. Replay residue in any cache is value-identical
//   (deterministic computation) hence benign.
#define WS_FRAG_BYTES (134217728ull)
#define WS_WCAT_OFF   (WS_FRAG_BYTES)
#define WS_WCAT_BYTES (4194304ull)
#define WS_H0_OFF     (WS_WCAT_OFF + WS_WCAT_BYTES)   // h0 bf16 [2][16][1024] = 64KB
#define WS_H1_OFF     (WS_H0_OFF + 65536ull)          // h1 bf16 [2][16][1024] = 64KB
#define WS_SENT_OFF   (WS_H1_OFF + 65536ull)          // 128 sentinels, 64B apart

__global__ void init_kernel(const float* __restrict__ Wa, const float* __restrict__ Wx,
                            const float* __restrict__ h0, float* __restrict__ hout0,
                            unsigned short* __restrict__ Wcat,
                            unsigned short* __restrict__ h0buf,
                            unsigned* __restrict__ sent)
{
  long i = (long)blockIdx.x * 256 + threadIdx.x;
  if (blockIdx.x == 0 && threadIdx.x < 128)
    __hip_atomic_store(&sent[threadIdx.x * 16], 0u, __ATOMIC_RELAXED, __HIP_MEMORY_SCOPE_AGENT);
  const long NW = 2048L * 1024L;
  for (long idx = i; idx < NW; idx += (long)gridDim.x * 256L){
    long r = idx >> 10, c = idx & 1023;
    float v = (r < 1024) ? Wa[r*1024 + c] : Wx[(r-1024)*1024 + c];
    Wcat[idx] = f2bf(v);
  }
  const long NH = 32L * 1024L;
  for (long idx = i; idx < NH; idx += (long)gridDim.x * 256L){
    float v = h0[idx];
    h0buf[idx] = f2bf(v);    // [b][col] == [2][16][1024] grouped
    hout0[idx] = v;          // hout[0] = h0 (fp32)
  }
}

__global__ __launch_bounds__(256) void pre_gemm(
    const float* __restrict__ x, const unsigned short* __restrict__ Wcat,
    const float* __restrict__ b_alpha, const float* __restrict__ b_x,
    unsigned short* __restrict__ frag)
{
  __shared__ unsigned short A_lds[128*72];
  __shared__ unsigned short B_lds[128*72];
  const int tid = threadIdx.x;
  const int lane = tid & 63;
  const int w = tid >> 6;
  const int wm = w >> 1, wn = w & 1;
  const long m0 = (long)blockIdx.y * 128;
  const int n0 = blockIdx.x * 128;

  floatx4 acc[4][4];
#pragma unroll
  for (int i=0;i<4;++i)
#pragma unroll
    for (int j=0;j<4;++j) acc[i][j] = (floatx4){0.f,0.f,0.f,0.f};

  for (int kt=0; kt<16; ++kt){
    const int k0 = kt*64;
    __syncthreads();
#pragma unroll
    for (int rep=0; rep<4; ++rep){
      int flat = rep*2048 + tid*8;
      int r = flat >> 6, c = flat & 63;
      const float* src = &x[(m0 + r)*1024 + k0 + c];
      floatx4 f0 = *(const floatx4*)src;
      floatx4 f1 = *(const floatx4*)(src + 4);
      short8 v;
      v[0]=(short)f2bf(f0[0]); v[1]=(short)f2bf(f0[1]); v[2]=(short)f2bf(f0[2]); v[3]=(short)f2bf(f0[3]);
      v[4]=(short)f2bf(f1[0]); v[5]=(short)f2bf(f1[1]); v[6]=(short)f2bf(f1[2]); v[7]=(short)f2bf(f1[3]);
      *(short8*)&A_lds[r*72 + c] = v;
      short8 bv = *(const short8*)&Wcat[(long)(n0 + r)*1024 + k0 + c];
      *(short8*)&B_lds[r*72 + c] = bv;
    }
    __syncthreads();
#pragma unroll
    for (int kb=0; kb<2; ++kb){
      short8 a[4], b[4];
#pragma unroll
      for (int f=0; f<4; ++f)
        a[f] = *(const short8*)&A_lds[(wm*64 + f*16 + (lane&15))*72 + kb*32 + (lane>>4)*8];
#pragma unroll
      for (int f=0; f<4; ++f)
        b[f] = *(const short8*)&B_lds[(wn*64 + f*16 + (lane&15))*72 + kb*32 + (lane>>4)*8];
#pragma unroll
      for (int fm=0; fm<4; ++fm)
#pragma unroll
        for (int fn=0; fn<4; ++fn)
          acc[fm][fn] = __builtin_amdgcn_mfma_f32_16x16x32_bf16(a[fm], b[fn], acc[fm][fn], 0, 0, 0);
    }
  }

#pragma unroll
  for (int fm=0; fm<4; ++fm){
    const long mrow = m0 + wm*64 + fm*16;
    const int t  = (int)(mrow >> 5);
    const int bh = (int)((mrow >> 4) & 1);
#pragma unroll
    for (int fn=0; fn<4; ++fn){
      const int nf  = n0 + wn*64 + fn*16;
      const int nt  = nf >> 4;
      const int col = nf + (lane & 15);
      floatx4 v = acc[fm][fn];
      const float bias = (col < DD) ? b_alpha[col] : b_x[col - DD];
      ushort4v o;
#pragma unroll
      for (int i=0;i<4;++i) o[i] = f2bf(v[i] + bias);
      *(ushort4v*)&frag[((((long)t*2 + bh)*128 + nt)*64 + lane)*4] = o;
    }
  }
}

// ---------------- scan: sentinel-gated plain exchange, W in regs, ping-pong LDS
__global__ __launch_bounds__(256, 1) void scan_kernel(
    const float* __restrict__ Wh, const float* __restrict__ h0,
    unsigned short* frag,
    const unsigned short* __restrict__ h0buf,
    unsigned short* h1buf,
    unsigned* sent)
{
  __shared__ unsigned h_lds[2][16*128*4];   // 2 x 32KB: [row][128 units x 16B]
  const int tid  = threadIdx.x;
  const int lane = tid & 63;
  const int w    = tid >> 6;
  const int bh   = blockIdx.x & 1;
  const int s    = blockIdx.x >> 1;
  const int base_r = s * 64;

  const int g8   = (lane >> 4) * 8;
  const int brow = w*16 + (lane & 15);

  // W_h slice row -> registers (fp32 load + convert, one-time)
  short8 Breg[32];
  {
    const float* Wr = &Wh[(long)(base_r + brow)*1024 + g8];
#pragma unroll
    for (int kb=0; kb<32; ++kb){
      floatx4 f0 = *(const floatx4*)&Wr[kb*32];
      floatx4 f1 = *(const floatx4*)&Wr[kb*32 + 4];
      short8 v;
      v[0]=(short)f2bf(f0[0]); v[1]=(short)f2bf(f0[1]); v[2]=(short)f2bf(f0[2]); v[3]=(short)f2bf(f0[3]);
      v[4]=(short)f2bf(f1[0]); v[5]=(short)f2bf(f1[1]); v[6]=(short)f2bf(f1[2]); v[7]=(short)f2bf(f1[3]);
      Breg[kb] = v;
    }
  }

  const int colf = base_r + w*16 + (lane & 15);
  const int nt_a = (base_r + w*16) >> 4;
  float hp[4];
#pragma unroll
  for (int i=0;i<4;++i){
    int gb = bh*16 + (lane>>4)*4 + i;
    hp[i] = h0[(long)gb*1024 + colf];
  }

  const int lrow  = tid >> 4;            // bulk-load/stage row (0..15)
  const int lcu   = tid & 15;            // unit lane
  const int swl   = (lrow & 7) ^ ((lrow & 1) << 3);   // write-side unit XOR
  const int row_a = lane & 15;           // MFMA A row
  const int swr   = (row_a & 7) ^ ((row_a & 1) << 3); // read-side unit XOR

  unsigned* mysent = sent + (bh*64 + s*4 + w)*16;
  unsigned* gsent  = sent + bh*64*16;

  // alpha via ATOMIC 8B (keeps alpha-half lines out of L1/L2), wx via plain
  long fb = (((long)0*2 + bh)*128 + nt_a)*64 + lane;
  unsigned long long a0v = __hip_atomic_load((const unsigned long long*)&frag[fb*4],
                                             __ATOMIC_RELAXED, __HIP_MEMORY_SCOPE_AGENT);
  ushort4v al = __builtin_bit_cast(ushort4v, a0v);
  ushort4v wx = *(const ushort4v*)&frag[(fb + 64*64)*4];

  for (int t=0; t<TT; ++t){
    // ---- sentinel poll: lane L watches wave-sentinel L of this group
    if (t > 0){
      for (;;){
        unsigned v = __hip_atomic_load(&gsent[lane*16],
                                       __ATOMIC_RELAXED, __HIP_MEMORY_SCOPE_AGENT);
        if (__all(v >= (unsigned)t)) break;
      }
      asm volatile("" ::: "memory");     // pin data loads after poll
    }

    // ---- bulk PLAIN load of group h (32KB/wg, coalesced, L2-shareable)
    const unsigned short* hsrc =
        (t == 0) ? (h0buf + bh*16384) :
        (t == 1) ? (h1buf + bh*16384) :
                   (frag + ((long)(t-2)*2 + bh)*32768);
    uint4v L[8];
#pragma unroll
    for (int j=0; j<8; ++j)
      L[j] = *(const uint4v*)&hsrc[lrow*1024 + (lcu + 16*j)*8];

    // ---- stage to ping-pong LDS (unit-XOR swizzle)
    unsigned* HB = h_lds[t & 1];
#pragma unroll
    for (int j=0; j<8; ++j){
      const int u = lcu + 16*j;
      *(uint4v*)&HB[(lrow*128 + (u ^ swl))*4] = L[j];
    }
    __syncthreads();   // the ONLY barrier per step

    // ---- MFMA from LDS vs Breg
    floatx4 ac0 = (floatx4){0.f,0.f,0.f,0.f}, ac1 = ac0, ac2 = ac0, ac3 = ac0;
#pragma unroll
    for (int kb=0; kb<32; ++kb){
      const int u = kb*4 + (lane>>4);
      uint4v q = *(const uint4v*)&HB[(row_a*128 + (u ^ swr))*4];
      short8 afr = __builtin_bit_cast(short8, q);
      if ((kb&3)==0) ac0 = __builtin_amdgcn_mfma_f32_16x16x32_bf16(afr, Breg[kb], ac0, 0, 0, 0);
      if ((kb&3)==1) ac1 = __builtin_amdgcn_mfma_f32_16x16x32_bf16(afr, Breg[kb], ac1, 0, 0, 0);
      if ((kb&3)==2) ac2 = __builtin_amdgcn_mfma_f32_16x16x32_bf16(afr, Breg[kb], ac2, 0, 0, 0);
      if ((kb&3)==3) ac3 = __builtin_amdgcn_mfma_f32_16x16x32_bf16(afr, Breg[kb], ac3, 0, 0, 0);
    }
    floatx4 acc = (ac0 + ac1) + (ac2 + ac3);

    // ---- epilogue: h_{t+1}; pack 4 cols via 2x shfl_xor; atomic 8B stores
    unsigned short* hD = (t == 0) ? (h1buf + bh*16384)
                                  : (frag + ((long)(t-1)*2 + bh)*32768);
    const int c4 = colf & ~3;            // 4-col aligned base
    const bool st4 = ((lane & 3) == 0);
#pragma unroll
    for (int i=0;i<4;++i){
      float sv = acc[i] + bf2f(wx[i]);
      float v  = fast_tanh(sv);
      float aa = sigm(bf2f(al[i]));
      float hn = aa*hp[i] + (1.0f - aa)*v;
      hp[i] = hn;
      unsigned us = (unsigned)f2bf(hn);
      unsigned p01 = us | ((unsigned)__shfl_xor((int)us, 1, 64) << 16); // (c,c+1) on even lanes
      unsigned p23 = (unsigned)__shfl_xor((int)p01, 2, 64);             // (c+2,c+3)
      if (st4){
        unsigned long long pv = ((unsigned long long)p23 << 32) | p01;
        const int r = (lane>>4)*4 + i;
        __hip_atomic_store((unsigned long long*)&hD[r*1024 + c4], pv,
                           __ATOMIC_RELAXED, __HIP_MEMORY_SCOPE_AGENT);
      }
    }

    // ---- drain data stores, then signal sentinel; then prefetch alpha/wx
    if (t + 1 < TT){
      asm volatile("s_waitcnt vmcnt(0)" ::: "memory");  // h stores at MALL (R8-proven)
      if (lane == 0)
        __hip_atomic_store(mysent, (unsigned)(t + 1),
                           __ATOMIC_RELAXED, __HIP_MEMORY_SCOPE_AGENT);
      fb = (((long)(t+1)*2 + bh)*128 + nt_a)*64 + lane;
      unsigned long long av = __hip_atomic_load((const unsigned long long*)&frag[fb*4],
                                                __ATOMIC_RELAXED, __HIP_MEMORY_SCOPE_AGENT);
      al = __builtin_bit_cast(ushort4v, av);
      wx = *(const ushort4v*)&frag[(fb + 64*64)*4];
    }
  }
}

// ---------------- expand bf16 h -> fp32 out/hout (off critical path)
__global__ __launch_bounds__(256) void out_writer(
    const unsigned short* __restrict__ frag,
    const unsigned short* __restrict__ h1buf,
    float* __restrict__ out, float* __restrict__ hout)
{
  const int t1 = blockIdx.z + 1;          // 1..1024
  const int bh = blockIdx.y;
  const int e  = (blockIdx.x*256 + threadIdx.x)*8;
  const int row = e >> 10, col = e & 1023;
  const unsigned short* src = (t1 == 1) ? (h1buf + bh*16384)
                                        : (frag + ((long)(t1-2)*2 + bh)*32768);
  short8 v = *(const short8*)&src[e];
  float o[8], hh[8];
#pragma unroll
  for (int j=0;j<8;++j){
    float h = bf2f((unsigned short)v[j]);
    float sg = sigm(h);
    hh[j] = h;
    o[j]  = h*h*sg;       // h * silu(h)
  }
  long ob = ((long)(t1-1)*BB + bh*16 + row)*DD + col;
  long hb = ((long)t1*BB + bh*16 + row)*DD + col;
  *(floatx4*)&out[ob]     = (floatx4){o[0],o[1],o[2],o[3]};
  *(floatx4*)&out[ob+4]   = (floatx4){o[4],o[5],o[6],o[7]};
  *(floatx4*)&hout[hb]    = (floatx4){hh[0],hh[1],hh[2],hh[3]};
  *(floatx4*)&hout[hb+4]  = (floatx4){hh[4],hh[5],hh[6],hh[7]};
}

extern "C" void kernel_launch(void* const* d_in, const int* in_sizes, int n_in,
                              void* d_out, int out_size, void* d_ws, size_t ws_size,
                              hipStream_t stream)
{
  const float* x  = (const float*)d_in[0];
  const float* h0 = (const float*)d_in[1];
  const float* Wa = (const float*)d_in[2];
  const float* ba = (const float*)d_in[3];
  const float* Wh = (const float*)d_in[4];
  const float* Wx = (const float*)d_in[5];
  const float* bx = (const float*)d_in[6];

  float* out  = (float*)d_out;
  float* hout = out + (long)TT*BB*DD;

  uint8_t* ws = (uint8_t*)d_ws;
  unsigned short* frag  = (unsigned short*)(ws);
  unsigned short* Wcat  = (unsigned short*)(ws + WS_WCAT_OFF);
  unsigned short* h0buf = (unsigned short*)(ws + WS_H0_OFF);
  unsigned short* h1buf = (unsigned short*)(ws + WS_H1_OFF);
  unsigned*       sent  = (unsigned*)      (ws + WS_SENT_OFF);

  init_kernel<<<8192, 256, 0, stream>>>(Wa, Wx, h0, hout, Wcat, h0buf, sent);
  pre_gemm<<<dim3(16, 256), 256, 0, stream>>>(x, Wcat, ba, bx, frag);
  scan_kernel<<<32, 256, 0, stream>>>(Wh, h0, frag, h0buf, h1buf, sent);
  out_writer<<<dim3(8, 2, 1024), 256, 0, stream>>>(frag, h1buf, out, hout);
}